// Round 1
// baseline (2302.882 us; speedup 1.0000x reference)
//
#include <hip/hip_runtime.h>
#include <math.h>

// Problem constants
// B=512, IN_CORES=12, N_PRIM=12, N_PAR=10, RFPC=4, RF=64, CAP=256
// out = (sigmoid MLP output (512,3072), x_sum (512,2560)) concatenated.

#define BATCH 512
#define OUT0_SZ (512*3072)

// ---------------------------------------------------------------------------
// Capsule layer 1: per (b,k) block. 256 threads = (l in 0..3) x (m in 0..63).
// routed[l,m] = sum_ij C1[i,j,k,l] * x[b, ij*64+m]   (C1 flat: ij*48 + k*4 + l)
// out[l,n]   = relu( sum_m routed[l,m]*W1[k,l,m,n] + b1[k,l,n] )
// ---------------------------------------------------------------------------
__global__ __launch_bounds__(256) void caps1_kernel(
    const float* __restrict__ x, const float* __restrict__ C1,
    const float* __restrict__ W1, const float* __restrict__ b1,
    float* __restrict__ xp)
{
    int k = blockIdx.x;          // 0..11
    int b = blockIdx.y;          // 0..511
    int tid = threadIdx.x;
    int l = tid >> 6, m = tid & 63;
    __shared__ float rsh[256];

    const float* xb = x + b * 3072;
    int cbase = k * 4 + l;
    float r = 0.f;
    #pragma unroll 4
    for (int ij = 0; ij < 48; ++ij) {
        r += C1[ij * 48 + cbase] * xb[ij * 64 + m];
    }
    rsh[tid] = r;
    __syncthreads();

    int n = m;
    const float* Wkl = W1 + (k * 4 + l) * 64 * 64;   // W1[k,l,m,n]
    const float* rl = rsh + l * 64;
    float acc = b1[(k * 4 + l) * 64 + n];
    #pragma unroll 8
    for (int mm = 0; mm < 64; ++mm) {
        acc += rl[mm] * Wkl[mm * 64 + n];
    }
    xp[b * 3072 + k * 256 + l * 64 + n] = fmaxf(acc, 0.f);
}

// ---------------------------------------------------------------------------
// Capsule layer 2 + skip: per (b,k), k in 0..9.
// sk[l,m]    = sum_ij C_skip[i,j,k,l]*xp[b,ij,m]   (flat: ij*40 + k*4 + l)
// routed[l,m]= sum_ij C2[i,j,k,l]  *xp[b,ij,m]
// x_sum[l,n] = sk[l,n] + relu( sum_m routed[l,m]*W2[k,l,m,n] + b2[k,l,n] )
// Thread (l,m) keeps sk in register; in phase 2 it is thread (l, n=m).
// ---------------------------------------------------------------------------
__global__ __launch_bounds__(256) void caps2_kernel(
    const float* __restrict__ xp, const float* __restrict__ Cs,
    const float* __restrict__ C2, const float* __restrict__ W2,
    const float* __restrict__ b2, float* __restrict__ xsum)
{
    int k = blockIdx.x;          // 0..9
    int b = blockIdx.y;
    int tid = threadIdx.x;
    int l = tid >> 6, m = tid & 63;
    __shared__ float rsh[256];

    const float* xb = xp + b * 3072;
    int cbase = k * 4 + l;
    float r = 0.f, sk = 0.f;
    #pragma unroll 4
    for (int ij = 0; ij < 48; ++ij) {
        float xv = xb[ij * 64 + m];
        r  += C2[ij * 40 + cbase] * xv;
        sk += Cs[ij * 40 + cbase] * xv;
    }
    rsh[tid] = r;
    __syncthreads();

    int n = m;
    const float* Wkl = W2 + (k * 4 + l) * 64 * 64;
    const float* rl = rsh + l * 64;
    float acc = b2[(k * 4 + l) * 64 + n];
    #pragma unroll 8
    for (int mm = 0; mm < 64; ++mm) {
        acc += rl[mm] * Wkl[mm * 64 + n];
    }
    xsum[b * 2560 + k * 256 + l * 64 + n] = sk + fmaxf(acc, 0.f);
}

// ---------------------------------------------------------------------------
// Per-sample: capsule norms (10 caps x 256), argmax (first-max wins, matching
// jnp.argmax), write masked x_recon.
// ---------------------------------------------------------------------------
__global__ __launch_bounds__(256) void mask_kernel(
    const float* __restrict__ xs, float* __restrict__ xrec)
{
    int b = blockIdx.x;
    int tid = threadIdx.x;
    int lane = tid & 63, wave = tid >> 6;
    __shared__ float part[4][10];
    __shared__ int act_sh;

    const float* xb = xs + b * 2560;
    for (int cap = 0; cap < 10; ++cap) {
        float v = xb[cap * 256 + tid];
        v = v * v;
        #pragma unroll
        for (int off = 32; off >= 1; off >>= 1)
            v += __shfl_down(v, off);
        if (lane == 0) part[wave][cap] = v;
    }
    __syncthreads();
    if (tid == 0) {
        int best = 0;
        float bn = -1.f;
        for (int cap = 0; cap < 10; ++cap) {
            float s = part[0][cap] + part[1][cap] + part[2][cap] + part[3][cap];
            if (s > bn) { bn = s; best = cap; }
        }
        act_sh = best;
    }
    __syncthreads();
    int act = act_sh;
    float* xr = xrec + b * 2560;
    #pragma unroll
    for (int r = 0; r < 10; ++r) {
        int idx = tid + r * 256;
        int cap = idx >> 8;
        xr[idx] = (cap == act) ? xb[idx] : 0.f;
    }
}

// ---------------------------------------------------------------------------
// Generic fp32 tiled GEMM: C[M,N] = act(A[M,K] @ B[K,N] + bias[N])
// 64x64 block tile, TK=32, 256 threads, 4x4 microtile.
// act: 0 = relu, 1 = sigmoid
// ---------------------------------------------------------------------------
__global__ __launch_bounds__(256) void gemm_bias_act(
    const float* __restrict__ A, const float* __restrict__ B,
    const float* __restrict__ bias, float* __restrict__ C,
    int M, int N, int K, int act)
{
    __shared__ float As[32][65];   // [k][m], padded +1 to kill store conflicts
    __shared__ float Bs[32][64];   // [k][n]

    int bn = blockIdx.x * 64;
    int bm = blockIdx.y * 64;
    int tid = threadIdx.x;
    int tx = tid & 15, ty = tid >> 4;

    float acc[4][4] = {{0.f}};

    for (int k0 = 0; k0 < K; k0 += 32) {
        // A tile: 64(m) x 32(k), transposed into As[k][m]
        #pragma unroll
        for (int r = 0; r < 8; ++r) {
            int idx = tid + r * 256;
            int mm = idx >> 5, kk = idx & 31;
            float v = 0.f;
            if (k0 + kk < K) v = A[(bm + mm) * K + k0 + kk];
            As[kk][mm] = v;
        }
        // B tile: 32(k) x 64(n)
        #pragma unroll
        for (int r = 0; r < 8; ++r) {
            int idx = tid + r * 256;
            int kk = idx >> 6, nn = idx & 63;
            float v = 0.f;
            if ((k0 + kk < K) && (bn + nn < N)) v = B[(k0 + kk) * N + bn + nn];
            Bs[kk][nn] = v;
        }
        __syncthreads();
        #pragma unroll
        for (int kk = 0; kk < 32; ++kk) {
            float a0 = As[kk][ty * 4 + 0];
            float a1 = As[kk][ty * 4 + 1];
            float a2 = As[kk][ty * 4 + 2];
            float a3 = As[kk][ty * 4 + 3];
            float b0 = Bs[kk][tx * 4 + 0];
            float b1 = Bs[kk][tx * 4 + 1];
            float b2 = Bs[kk][tx * 4 + 2];
            float b3 = Bs[kk][tx * 4 + 3];
            acc[0][0] += a0 * b0; acc[0][1] += a0 * b1; acc[0][2] += a0 * b2; acc[0][3] += a0 * b3;
            acc[1][0] += a1 * b0; acc[1][1] += a1 * b1; acc[1][2] += a1 * b2; acc[1][3] += a1 * b3;
            acc[2][0] += a2 * b0; acc[2][1] += a2 * b1; acc[2][2] += a2 * b2; acc[2][3] += a2 * b3;
            acc[3][0] += a3 * b0; acc[3][1] += a3 * b1; acc[3][2] += a3 * b2; acc[3][3] += a3 * b3;
        }
        __syncthreads();
    }

    #pragma unroll
    for (int i = 0; i < 4; ++i) {
        int m = bm + ty * 4 + i;
        #pragma unroll
        for (int j = 0; j < 4; ++j) {
            int n = bn + tx * 4 + j;
            if (n < N) {
                float v = acc[i][j] + bias[n];
                if (act == 0) v = fmaxf(v, 0.f);
                else          v = 1.f / (1.f + expf(-v));
                C[m * N + n] = v;
            }
        }
    }
}

extern "C" void kernel_launch(void* const* d_in, const int* in_sizes, int n_in,
                              void* d_out, int out_size, void* d_ws, size_t ws_size,
                              hipStream_t stream) {
    const float* x   = (const float*)d_in[0];
    const float* C1  = (const float*)d_in[1];
    const float* W1  = (const float*)d_in[2];
    const float* b1  = (const float*)d_in[3];
    const float* Cs  = (const float*)d_in[4];
    const float* C2  = (const float*)d_in[5];
    const float* W2  = (const float*)d_in[6];
    const float* b2  = (const float*)d_in[7];
    const float* Wr1 = (const float*)d_in[8];
    const float* br1 = (const float*)d_in[9];
    const float* Wr2 = (const float*)d_in[10];
    const float* br2 = (const float*)d_in[11];
    const float* Wr3 = (const float*)d_in[12];
    const float* br3 = (const float*)d_in[13];

    float* out = (float*)d_out;
    float* out0     = out;              // (512,3072) sigmoid MLP output
    float* xsum_out = out + OUT0_SZ;    // (512,2560) x_sum

    float* ws   = (float*)d_ws;
    float* xp   = ws;                   // 512*3072 = 1572864
    float* xrec = xp   + 512 * 3072;    // 512*2560 = 1310720
    float* h1   = xrec + 512 * 2560;    // 512*5000 = 2560000
    float* h2   = h1   + 512 * 5000;    // 512*4000 = 2048000

    // Capsule layers
    caps1_kernel<<<dim3(12, BATCH), 256, 0, stream>>>(x, C1, W1, b1, xp);
    caps2_kernel<<<dim3(10, BATCH), 256, 0, stream>>>(xp, Cs, C2, W2, b2, xsum_out);
    // Norm/argmax/mask
    mask_kernel<<<BATCH, 256, 0, stream>>>(xsum_out, xrec);
    // Reconstruction MLP
    gemm_bias_act<<<dim3(79, 8), 256, 0, stream>>>(xrec, Wr1, br1, h1, 512, 5000, 2560, 0);
    gemm_bias_act<<<dim3(63, 8), 256, 0, stream>>>(h1,   Wr2, br2, h2, 512, 4000, 5000, 0);
    gemm_bias_act<<<dim3(48, 8), 256, 0, stream>>>(h2,   Wr3, br3, out0, 512, 3072, 4000, 1);
}

// Round 2
// 779.539 us; speedup vs baseline: 2.9542x; 2.9542x over previous
//
#include <hip/hip_runtime.h>
#include <math.h>

// B=512, IN_CORES=12, N_PRIM=12, N_PAR=10, RFPC=4, RF=64, CAP=256
// out = concat( sigmoid MLP output (512,3072) f32 , x_sum (512,2560) f32 )

#define BATCH 512
#define OUT0_SZ (512*3072)

typedef __attribute__((ext_vector_type(8))) short short8;   // 8 x bf16
typedef __attribute__((ext_vector_type(4))) float f32x4;

__device__ inline unsigned short f2bf(float f) {
    union { float f; unsigned u; } v; v.f = f;
    unsigned r = v.u + 0x7fffu + ((v.u >> 16) & 1u);   // RNE
    return (unsigned short)(r >> 16);
}

// ---------------------------------------------------------------------------
// Capsule layer 1 (fp32, exact)
// ---------------------------------------------------------------------------
__global__ __launch_bounds__(256) void caps1_kernel(
    const float* __restrict__ x, const float* __restrict__ C1,
    const float* __restrict__ W1, const float* __restrict__ b1,
    float* __restrict__ xp)
{
    int k = blockIdx.x;          // 0..11
    int b = blockIdx.y;          // 0..511
    int tid = threadIdx.x;
    int l = tid >> 6, m = tid & 63;
    __shared__ float rsh[256];

    const float* xb = x + b * 3072;
    int cbase = k * 4 + l;
    float r = 0.f;
    #pragma unroll 4
    for (int ij = 0; ij < 48; ++ij) {
        r += C1[ij * 48 + cbase] * xb[ij * 64 + m];
    }
    rsh[tid] = r;
    __syncthreads();

    int n = m;
    const float* Wkl = W1 + (k * 4 + l) * 64 * 64;
    const float* rl = rsh + l * 64;
    float acc = b1[(k * 4 + l) * 64 + n];
    #pragma unroll 8
    for (int mm = 0; mm < 64; ++mm) {
        acc += rl[mm] * Wkl[mm * 64 + n];
    }
    xp[b * 3072 + k * 256 + l * 64 + n] = fmaxf(acc, 0.f);
}

// ---------------------------------------------------------------------------
// Capsule layer 2 + skip (fp32, exact)
// ---------------------------------------------------------------------------
__global__ __launch_bounds__(256) void caps2_kernel(
    const float* __restrict__ xp, const float* __restrict__ Cs,
    const float* __restrict__ C2, const float* __restrict__ W2,
    const float* __restrict__ b2, float* __restrict__ xsum)
{
    int k = blockIdx.x;          // 0..9
    int b = blockIdx.y;
    int tid = threadIdx.x;
    int l = tid >> 6, m = tid & 63;
    __shared__ float rsh[256];

    const float* xb = xp + b * 3072;
    int cbase = k * 4 + l;
    float r = 0.f, sk = 0.f;
    #pragma unroll 4
    for (int ij = 0; ij < 48; ++ij) {
        float xv = xb[ij * 64 + m];
        r  += C2[ij * 40 + cbase] * xv;
        sk += Cs[ij * 40 + cbase] * xv;
    }
    rsh[tid] = r;
    __syncthreads();

    int n = m;
    const float* Wkl = W2 + (k * 4 + l) * 64 * 64;
    const float* rl = rsh + l * 64;
    float acc = b2[(k * 4 + l) * 64 + n];
    #pragma unroll 8
    for (int mm = 0; mm < 64; ++mm) {
        acc += rl[mm] * Wkl[mm * 64 + n];
    }
    xsum[b * 2560 + k * 256 + l * 64 + n] = sk + fmaxf(acc, 0.f);
}

// ---------------------------------------------------------------------------
// Norm/argmax/mask; writes x_recon as bf16 (input to MFMA GEMM chain)
// ---------------------------------------------------------------------------
__global__ __launch_bounds__(256) void mask_kernel(
    const float* __restrict__ xs, unsigned short* __restrict__ xrec)
{
    int b = blockIdx.x;
    int tid = threadIdx.x;
    int lane = tid & 63, wave = tid >> 6;
    __shared__ float part[4][10];
    __shared__ int act_sh;

    const float* xb = xs + b * 2560;
    for (int cap = 0; cap < 10; ++cap) {
        float v = xb[cap * 256 + tid];
        v = v * v;
        #pragma unroll
        for (int off = 32; off >= 1; off >>= 1)
            v += __shfl_down(v, off);
        if (lane == 0) part[wave][cap] = v;
    }
    __syncthreads();
    if (tid == 0) {
        int best = 0;
        float bn = -1.f;
        for (int cap = 0; cap < 10; ++cap) {
            float s = part[0][cap] + part[1][cap] + part[2][cap] + part[3][cap];
            if (s > bn) { bn = s; best = cap; }
        }
        act_sh = best;
    }
    __syncthreads();
    int act = act_sh;
    unsigned short* xr = xrec + b * 2560;
    #pragma unroll
    for (int r = 0; r < 10; ++r) {
        int idx = tid + r * 256;
        int cap = idx >> 8;
        float v = (cap == act) ? xb[idx] : 0.f;
        xr[idx] = f2bf(v);
    }
}

// ---------------------------------------------------------------------------
// MFMA bf16 GEMM: C[M,Np] = act(A[M,Kp](bf16) @ B[K_real,N_real](f32->bf16) + bias)
// Block tile 64(M) x 128(N), BK=32. 256 threads = 4 waves, each wave 64x32
// (4x2 grid of 16x16x32 MFMA). LDS tiles stored [row][k] padded to 40 shorts
// (80 B stride -> 2-way bank aliasing, free).
// MODE 0: relu, store bf16 (ldC = Np).  MODE 1: sigmoid, store f32.
// Pad region (n >= N_real or k >= K_real) reads as 0 -> pad outputs = 0.
// ---------------------------------------------------------------------------
template<int MODE>
__global__ __launch_bounds__(256) void gemm_mfma(
    const unsigned short* __restrict__ A, int ldA,
    const float* __restrict__ B, int N_real, int K_real,
    const float* __restrict__ bias, void* __restrict__ Cout, int ldC,
    int Kp)
{
    __shared__ __align__(16) unsigned short As[64 * 40];
    __shared__ __align__(16) unsigned short Bs[128 * 40];

    int tid = threadIdx.x;
    int bn = blockIdx.x * 128;
    int bm = blockIdx.y * 64;

    int w = tid >> 6;            // wave 0..3 -> n-slice
    int lane = tid & 63;
    int q = lane >> 4;           // quad 0..3
    int r16 = lane & 15;
    int wn = w * 32;

    // staging indices
    int am = tid >> 2, aq = tid & 3;          // A: row, 16-byte quarter
    int bnn = tid & 127, bkg = tid >> 7;      // B: col, k-half (0..1)
    int gn = bn + bnn;
    bool nok = gn < N_real;

    f32x4 acc[4][2];
    #pragma unroll
    for (int mt = 0; mt < 4; ++mt)
        #pragma unroll
        for (int nt = 0; nt < 2; ++nt)
            acc[mt][nt] = (f32x4)0.f;

    for (int k0 = 0; k0 < Kp; k0 += 32) {
        // --- stage A tile: 64 x 32 bf16, already bf16 in global ---
        {
            const float4* ap = (const float4*)(A + (size_t)(bm + am) * ldA + k0 + aq * 8);
            *(float4*)&As[am * 40 + aq * 8] = *ap;
        }
        // --- stage B tile: 32 x 128 fp32 -> bf16, transposed to [n][k] ---
        {
            const float* bp = B + (size_t)(k0 + bkg * 16) * N_real + gn;
            unsigned int u[8];
            #pragma unroll
            for (int r = 0; r < 8; ++r) {
                int gk0 = k0 + bkg * 16 + 2 * r;
                float v0 = (nok && (gk0     < K_real)) ? bp[(size_t)(2 * r    ) * N_real] : 0.f;
                float v1 = (nok && (gk0 + 1 < K_real)) ? bp[(size_t)(2 * r + 1) * N_real] : 0.f;
                u[r] = (unsigned int)f2bf(v0) | ((unsigned int)f2bf(v1) << 16);
            }
            unsigned int* dst = (unsigned int*)&Bs[bnn * 40 + bkg * 16];
            *(uint4*)(dst)     = make_uint4(u[0], u[1], u[2], u[3]);
            *(uint4*)(dst + 4) = make_uint4(u[4], u[5], u[6], u[7]);
        }
        __syncthreads();

        short8 a[4], b[2];
        #pragma unroll
        for (int mt = 0; mt < 4; ++mt)
            a[mt] = *(const short8*)&As[(mt * 16 + r16) * 40 + q * 8];
        #pragma unroll
        for (int nt = 0; nt < 2; ++nt)
            b[nt] = *(const short8*)&Bs[(wn + nt * 16 + r16) * 40 + q * 8];
        #pragma unroll
        for (int mt = 0; mt < 4; ++mt)
            #pragma unroll
            for (int nt = 0; nt < 2; ++nt)
                acc[mt][nt] = __builtin_amdgcn_mfma_f32_16x16x32_bf16(a[mt], b[nt], acc[mt][nt], 0, 0, 0);
        __syncthreads();
    }

    // --- epilogue ---
    #pragma unroll
    for (int mt = 0; mt < 4; ++mt) {
        #pragma unroll
        for (int nt = 0; nt < 2; ++nt) {
            int cn = bn + wn + nt * 16 + r16;
            float bv = (cn < N_real) ? bias[cn] : 0.f;
            #pragma unroll
            for (int reg = 0; reg < 4; ++reg) {
                int cm = bm + mt * 16 + q * 4 + reg;
                float v = acc[mt][nt][reg] + bv;
                if (MODE == 0) {
                    v = fmaxf(v, 0.f);
                    ((unsigned short*)Cout)[(size_t)cm * ldC + cn] = f2bf(v);
                } else {
                    v = 1.f / (1.f + expf(-v));
                    ((float*)Cout)[(size_t)cm * ldC + cn] = v;
                }
            }
        }
    }
}

extern "C" void kernel_launch(void* const* d_in, const int* in_sizes, int n_in,
                              void* d_out, int out_size, void* d_ws, size_t ws_size,
                              hipStream_t stream) {
    const float* x   = (const float*)d_in[0];
    const float* C1  = (const float*)d_in[1];
    const float* W1  = (const float*)d_in[2];
    const float* b1  = (const float*)d_in[3];
    const float* Cs  = (const float*)d_in[4];
    const float* C2  = (const float*)d_in[5];
    const float* W2  = (const float*)d_in[6];
    const float* b2  = (const float*)d_in[7];
    const float* Wr1 = (const float*)d_in[8];
    const float* br1 = (const float*)d_in[9];
    const float* Wr2 = (const float*)d_in[10];
    const float* br2 = (const float*)d_in[11];
    const float* Wr3 = (const float*)d_in[12];
    const float* br3 = (const float*)d_in[13];

    float* out = (float*)d_out;
    float* out0     = out;              // (512,3072) sigmoid MLP output (f32)
    float* xsum_out = out + OUT0_SZ;    // (512,2560) x_sum (f32, exact)

    // workspace layout (16B-aligned)
    char* base = (char*)d_ws;
    float*          xp   = (float*)base;                       // 512*3072 f32  = 6291456 B
    unsigned short* xrec = (unsigned short*)(base + 6291456);  // 512*2560 bf16 = 2621440 B
    unsigned short* h1   = (unsigned short*)(base + 8912896);  // 512*5120 bf16 = 5242880 B
    unsigned short* h2   = (unsigned short*)(base + 14155776); // 512*4096 bf16 = 4194304 B

    // Capsule layers (exact fp32 -> output 1)
    caps1_kernel<<<dim3(12, BATCH), 256, 0, stream>>>(x, C1, W1, b1, xp);
    caps2_kernel<<<dim3(10, BATCH), 256, 0, stream>>>(xp, Cs, C2, W2, b2, xsum_out);
    mask_kernel<<<BATCH, 256, 0, stream>>>(xsum_out, xrec);

    // Reconstruction MLP: bf16 MFMA, padded dims (5000->5120, 4000->4096)
    gemm_mfma<0><<<dim3(5120 / 128, 8), 256, 0, stream>>>(
        xrec, 2560, Wr1, 5000, 2560, br1, h1, 5120, 2560);
    gemm_mfma<0><<<dim3(4096 / 128, 8), 256, 0, stream>>>(
        h1, 5120, Wr2, 4000, 5000, br2, h2, 4096, 5120);
    gemm_mfma<1><<<dim3(3072 / 128, 8), 256, 0, stream>>>(
        h2, 4096, Wr3, 3072, 4000, br3, out0, 3072, 4096);
}

// Round 3
// 465.918 us; speedup vs baseline: 4.9427x; 1.6731x over previous
//
#include <hip/hip_runtime.h>
#include <math.h>

// B=512, IN_CORES=12, N_PRIM=12, N_PAR=10, RFPC=4, RF=64, CAP=256
// out = concat( sigmoid MLP output (512,3072) f32 , x_sum (512,2560) f32 )

#define BATCH 512
#define OUT0_SZ (512*3072)

typedef __attribute__((ext_vector_type(8))) short short8;   // 8 x bf16
typedef __attribute__((ext_vector_type(4))) float f32x4;

__device__ inline unsigned short f2bf(float f) {
    union { float f; unsigned u; } v; v.f = f;
    unsigned r = v.u + 0x7fffu + ((v.u >> 16) & 1u);   // RNE
    return (unsigned short)(r >> 16);
}

// async global->LDS, 16 bytes per lane
#define GLD16(g, l) __builtin_amdgcn_global_load_lds( \
    (const __attribute__((address_space(1))) unsigned int*)(g), \
    (__attribute__((address_space(3))) unsigned int*)(l), 16, 0, 0)

// ---------------------------------------------------------------------------
// Capsule layer 1 (fp32, exact)
// ---------------------------------------------------------------------------
__global__ __launch_bounds__(256) void caps1_kernel(
    const float* __restrict__ x, const float* __restrict__ C1,
    const float* __restrict__ W1, const float* __restrict__ b1,
    float* __restrict__ xp)
{
    int k = blockIdx.x;          // 0..11
    int b = blockIdx.y;          // 0..511
    int tid = threadIdx.x;
    int l = tid >> 6, m = tid & 63;
    __shared__ float rsh[256];

    const float* xb = x + b * 3072;
    int cbase = k * 4 + l;
    float r = 0.f;
    #pragma unroll 4
    for (int ij = 0; ij < 48; ++ij) {
        r += C1[ij * 48 + cbase] * xb[ij * 64 + m];
    }
    rsh[tid] = r;
    __syncthreads();

    int n = m;
    const float* Wkl = W1 + (k * 4 + l) * 64 * 64;
    const float* rl = rsh + l * 64;
    float acc = b1[(k * 4 + l) * 64 + n];
    #pragma unroll 8
    for (int mm = 0; mm < 64; ++mm) {
        acc += rl[mm] * Wkl[mm * 64 + n];
    }
    xp[b * 3072 + k * 256 + l * 64 + n] = fmaxf(acc, 0.f);
}

// ---------------------------------------------------------------------------
// Capsule layer 2 + skip (fp32, exact)
// ---------------------------------------------------------------------------
__global__ __launch_bounds__(256) void caps2_kernel(
    const float* __restrict__ xp, const float* __restrict__ Cs,
    const float* __restrict__ C2, const float* __restrict__ W2,
    const float* __restrict__ b2, float* __restrict__ xsum)
{
    int k = blockIdx.x;          // 0..9
    int b = blockIdx.y;
    int tid = threadIdx.x;
    int l = tid >> 6, m = tid & 63;
    __shared__ float rsh[256];

    const float* xb = xp + b * 3072;
    int cbase = k * 4 + l;
    float r = 0.f, sk = 0.f;
    #pragma unroll 4
    for (int ij = 0; ij < 48; ++ij) {
        float xv = xb[ij * 64 + m];
        r  += C2[ij * 40 + cbase] * xv;
        sk += Cs[ij * 40 + cbase] * xv;
    }
    rsh[tid] = r;
    __syncthreads();

    int n = m;
    const float* Wkl = W2 + (k * 4 + l) * 64 * 64;
    const float* rl = rsh + l * 64;
    float acc = b2[(k * 4 + l) * 64 + n];
    #pragma unroll 8
    for (int mm = 0; mm < 64; ++mm) {
        acc += rl[mm] * Wkl[mm * 64 + n];
    }
    xsum[b * 2560 + k * 256 + l * 64 + n] = sk + fmaxf(acc, 0.f);
}

// ---------------------------------------------------------------------------
// Norm/argmax/mask; writes x_recon as bf16
// ---------------------------------------------------------------------------
__global__ __launch_bounds__(256) void mask_kernel(
    const float* __restrict__ xs, unsigned short* __restrict__ xrec)
{
    int b = blockIdx.x;
    int tid = threadIdx.x;
    int lane = tid & 63, wave = tid >> 6;
    __shared__ float part[4][10];
    __shared__ int act_sh;

    const float* xb = xs + b * 2560;
    for (int cap = 0; cap < 10; ++cap) {
        float v = xb[cap * 256 + tid];
        v = v * v;
        #pragma unroll
        for (int off = 32; off >= 1; off >>= 1)
            v += __shfl_down(v, off);
        if (lane == 0) part[wave][cap] = v;
    }
    __syncthreads();
    if (tid == 0) {
        int best = 0;
        float bn = -1.f;
        for (int cap = 0; cap < 10; ++cap) {
            float s = part[0][cap] + part[1][cap] + part[2][cap] + part[3][cap];
            if (s > bn) { bn = s; best = cap; }
        }
        act_sh = best;
    }
    __syncthreads();
    int act = act_sh;
    unsigned short* xr = xrec + b * 2560;
    #pragma unroll
    for (int r = 0; r < 10; ++r) {
        int idx = tid + r * 256;
        int cap = idx >> 8;
        float v = (cap == act) ? xb[idx] : 0.f;
        xr[idx] = f2bf(v);
    }
}

// ---------------------------------------------------------------------------
// Weight convert + transpose: W[Kr][Nr] f32 -> Wt[Np][Kp] bf16, zero-padded.
// 32x32 tiles via LDS. Grid: (Kp/32, Np/32), 256 threads.
// ---------------------------------------------------------------------------
__global__ __launch_bounds__(256) void convT_kernel(
    const float* __restrict__ W, unsigned short* __restrict__ Wt,
    int Kr, int Nr, int Kp, int Np)
{
    __shared__ float tile[32][33];
    int k0 = blockIdx.x * 32;
    int n0 = blockIdx.y * 32;
    int tid = threadIdx.x;
    int c = tid & 31, r8 = tid >> 5;

    #pragma unroll
    for (int rr = 0; rr < 4; ++rr) {
        int row = r8 + rr * 8;                 // k offset
        float v = 0.f;
        if ((k0 + row < Kr) && (n0 + c < Nr))
            v = W[(size_t)(k0 + row) * Nr + n0 + c];
        tile[row][c] = v;
    }
    __syncthreads();
    #pragma unroll
    for (int rr = 0; rr < 4; ++rr) {
        int rowN = r8 + rr * 8;                // n offset
        Wt[(size_t)(n0 + rowN) * Kp + k0 + c] = f2bf(tile[c][rowN]);
    }
}

// ---------------------------------------------------------------------------
// Split-K MFMA GEMM (m97 structure): P[z] += A[M,Kp] @ Bt[Np,Kp]^T
// 128x128 tile, BK=32, 256 threads = 4 waves (2x2), each wave 64x64 = 4x4
// frags of 16x16x32. A,Bt bf16 row-major; staging via global_load_lds(16B).
// LDS rows = 64 B -> 2-way bank aliasing (free). Partial fp32 out.
// Grid: (Np/128, M/128, SPLITK). kper = Kp/SPLITK (multiple of 32).
// ---------------------------------------------------------------------------
#define SPLITK 4
__global__ __launch_bounds__(256) void gemm_splitk(
    const unsigned short* __restrict__ A, int ldA,
    const unsigned short* __restrict__ Bt, int ldB,
    float* __restrict__ P, int Np, int kper)
{
    __shared__ __align__(16) unsigned short As[128 * 32];
    __shared__ __align__(16) unsigned short Bs[128 * 32];

    int tid = threadIdx.x;
    int bn = blockIdx.x * 128;
    int bm = blockIdx.y * 128;
    int kz = blockIdx.z * kper;

    int w = tid >> 6, lane = tid & 63;
    int wm = (w >> 1) * 64, wn = (w & 1) * 64;
    int q = lane >> 4, r16 = lane & 15;

    int srow = tid >> 2, skq = tid & 3;   // staging: chunk c=tid -> (row,kq); c=tid+256 -> (row+64,kq)

    f32x4 acc[4][4];
    #pragma unroll
    for (int i = 0; i < 4; ++i)
        #pragma unroll
        for (int j = 0; j < 4; ++j) acc[i][j] = (f32x4)0.f;

    for (int kk = 0; kk < kper; kk += 32) {
        int k0 = kz + kk;
        const unsigned short* ga = A + (size_t)(bm + srow) * ldA + k0 + skq * 8;
        GLD16(ga, &As[tid * 8]);
        GLD16(ga + (size_t)64 * ldA, &As[(tid + 256) * 8]);
        const unsigned short* gb = Bt + (size_t)(bn + srow) * ldB + k0 + skq * 8;
        GLD16(gb, &Bs[tid * 8]);
        GLD16(gb + (size_t)64 * ldB, &Bs[(tid + 256) * 8]);
        __syncthreads();

        short8 a[4], b[4];
        #pragma unroll
        for (int mt = 0; mt < 4; ++mt)
            a[mt] = *(const short8*)&As[(wm + mt * 16 + r16) * 32 + q * 8];
        #pragma unroll
        for (int nt = 0; nt < 4; ++nt)
            b[nt] = *(const short8*)&Bs[(wn + nt * 16 + r16) * 32 + q * 8];
        #pragma unroll
        for (int mt = 0; mt < 4; ++mt)
            #pragma unroll
            for (int nt = 0; nt < 4; ++nt)
                acc[mt][nt] = __builtin_amdgcn_mfma_f32_16x16x32_bf16(a[mt], b[nt], acc[mt][nt], 0, 0, 0);
        __syncthreads();
    }

    float* Pz = P + (size_t)blockIdx.z * 512 * Np;
    #pragma unroll
    for (int mt = 0; mt < 4; ++mt) {
        #pragma unroll
        for (int nt = 0; nt < 4; ++nt) {
            int cn = bn + wn + nt * 16 + r16;
            #pragma unroll
            for (int reg = 0; reg < 4; ++reg) {
                int cm = bm + wm + mt * 16 + q * 4 + reg;
                Pz[(size_t)cm * Np + cn] = acc[mt][nt][reg];
            }
        }
    }
}

// ---------------------------------------------------------------------------
// Combine split-K partials + bias + act.
// MODE 0: relu -> bf16 (pitch Np). MODE 1: sigmoid -> f32 (pitch Np).
// Each thread: 4 consecutive n. N_real multiple of 4.
// ---------------------------------------------------------------------------
template<int MODE>
__global__ __launch_bounds__(256) void combine_kernel(
    const float* __restrict__ P, const float* __restrict__ bias,
    void* __restrict__ out, int Np, int N_real)
{
    int gid = blockIdx.x * 256 + threadIdx.x;
    int n0 = (gid * 4) % Np;
    int m  = (gid * 4) / Np;
    size_t MN = (size_t)512 * Np;
    const float* p = P + (size_t)m * Np + n0;
    f32x4 s = *(const f32x4*)p;
    s += *(const f32x4*)(p + MN);
    s += *(const f32x4*)(p + 2 * MN);
    s += *(const f32x4*)(p + 3 * MN);
    f32x4 bv = (n0 < N_real) ? *(const f32x4*)(bias + n0) : (f32x4)0.f;
    s += bv;
    if (MODE == 0) {
        unsigned int lo = (unsigned int)f2bf(fmaxf(s[0], 0.f)) | ((unsigned int)f2bf(fmaxf(s[1], 0.f)) << 16);
        unsigned int hi = (unsigned int)f2bf(fmaxf(s[2], 0.f)) | ((unsigned int)f2bf(fmaxf(s[3], 0.f)) << 16);
        *(uint2*)((unsigned short*)out + (size_t)m * Np + n0) = make_uint2(lo, hi);
    } else {
        f32x4 v;
        v[0] = 1.f / (1.f + expf(-s[0]));
        v[1] = 1.f / (1.f + expf(-s[1]));
        v[2] = 1.f / (1.f + expf(-s[2]));
        v[3] = 1.f / (1.f + expf(-s[3]));
        *(f32x4*)((float*)out + (size_t)m * Np + n0) = v;
    }
}

extern "C" void kernel_launch(void* const* d_in, const int* in_sizes, int n_in,
                              void* d_out, int out_size, void* d_ws, size_t ws_size,
                              hipStream_t stream) {
    const float* x   = (const float*)d_in[0];
    const float* C1  = (const float*)d_in[1];
    const float* W1  = (const float*)d_in[2];
    const float* b1  = (const float*)d_in[3];
    const float* Cs  = (const float*)d_in[4];
    const float* C2  = (const float*)d_in[5];
    const float* W2  = (const float*)d_in[6];
    const float* b2  = (const float*)d_in[7];
    const float* Wr1 = (const float*)d_in[8];
    const float* br1 = (const float*)d_in[9];
    const float* Wr2 = (const float*)d_in[10];
    const float* br2 = (const float*)d_in[11];
    const float* Wr3 = (const float*)d_in[12];
    const float* br3 = (const float*)d_in[13];

    float* out = (float*)d_out;
    float* out0     = out;              // (512,3072) f32 sigmoid output
    float* xsum_out = out + OUT0_SZ;    // (512,2560) f32 x_sum (exact)

    // workspace layout (bytes)
    char* base = (char*)d_ws;
    float*          xp   = (float*)(base);                      //  6,291,456
    unsigned short* xrec = (unsigned short*)(base +  6291456);  //  2,621,440
    unsigned short* h1   = (unsigned short*)(base +  8912896);  //  5,242,880
    unsigned short* h2   = (unsigned short*)(base + 14155776);  //  4,194,304
    unsigned short* Wt   = (unsigned short*)(base + 18350080);  // 41,943,040 (shared per layer)
    float*          Pbuf = (float*)(base + 60293120);           // 41,943,040 (split-K partials)
    // total: 102,236,160 B

    // --- capsule path (exact fp32 -> output 1) ---
    caps1_kernel<<<dim3(12, BATCH), 256, 0, stream>>>(x, C1, W1, b1, xp);
    caps2_kernel<<<dim3(10, BATCH), 256, 0, stream>>>(xp, Cs, C2, W2, b2, xsum_out);
    mask_kernel<<<BATCH, 256, 0, stream>>>(xsum_out, xrec);

    // --- layer 1: (512,2560) @ (2560,5000) -> h1 (512,5120 bf16) ---
    convT_kernel<<<dim3(2560 / 32, 5120 / 32), 256, 0, stream>>>(Wr1, Wt, 2560, 5000, 2560, 5120);
    gemm_splitk<<<dim3(5120 / 128, 4, SPLITK), 256, 0, stream>>>(xrec, 2560, Wt, 2560, Pbuf, 5120, 2560 / SPLITK);
    combine_kernel<0><<<512 * 5120 / 1024, 256, 0, stream>>>(Pbuf, br1, h1, 5120, 5000);

    // --- layer 2: (512,5120) @ (5120,4000) -> h2 (512,4096 bf16) ---
    convT_kernel<<<dim3(5120 / 32, 4096 / 32), 256, 0, stream>>>(Wr2, Wt, 5000, 4000, 5120, 4096);
    gemm_splitk<<<dim3(4096 / 128, 4, SPLITK), 256, 0, stream>>>(h1, 5120, Wt, 5120, Pbuf, 4096, 5120 / SPLITK);
    combine_kernel<0><<<512 * 4096 / 1024, 256, 0, stream>>>(Pbuf, br2, h2, 4096, 4000);

    // --- layer 3: (512,4096) @ (4096,3072) -> out0 (512,3072 f32, sigmoid) ---
    convT_kernel<<<dim3(4096 / 32, 3072 / 32), 256, 0, stream>>>(Wr3, Wt, 4000, 3072, 4096, 3072);
    gemm_splitk<<<dim3(3072 / 128, 4, SPLITK), 256, 0, stream>>>(h2, 4096, Wt, 4096, Pbuf, 3072, 4096 / SPLITK);
    combine_kernel<1><<<512 * 3072 / 1024, 256, 0, stream>>>(Pbuf, br3, out0, 3072, 3072);
}

// Round 4
// 438.249 us; speedup vs baseline: 5.2547x; 1.0631x over previous
//
#include <hip/hip_runtime.h>
#include <math.h>

// B=512, IN_CORES=12, N_PRIM=12, N_PAR=10, RFPC=4, RF=64, CAP=256
// out = concat( sigmoid MLP output (512,3072) f32 , x_sum (512,2560) f32 )

#define BATCH 512
#define OUT0_SZ (512*3072)

typedef __attribute__((ext_vector_type(8))) short short8;   // 8 x bf16
typedef __attribute__((ext_vector_type(4))) float f32x4;

__device__ inline unsigned short f2bf(float f) {
    union { float f; unsigned u; } v; v.f = f;
    unsigned r = v.u + 0x7fffu + ((v.u >> 16) & 1u);   // RNE
    return (unsigned short)(r >> 16);
}

// async global->LDS, 16 bytes per lane
#define GLD16(g, l) __builtin_amdgcn_global_load_lds( \
    (const __attribute__((address_space(1))) unsigned int*)(g), \
    (__attribute__((address_space(3))) unsigned int*)(l), 16, 0, 0)

// ---------------------------------------------------------------------------
// Capsule layer 1 (fp32, exact). Grid (256, 2): 2 batch rows per block,
// 6 capsules per k-group. x staged in LDS once (was re-read 12x).
// Each thread computes 2 batch samples per W element (2 FMA per W load).
// ---------------------------------------------------------------------------
__global__ __launch_bounds__(256) void caps1_kernel(
    const float* __restrict__ x, const float* __restrict__ C1,
    const float* __restrict__ W1, const float* __restrict__ b1,
    float* __restrict__ xp)
{
    __shared__ float xb0[3072], xb1[3072];
    __shared__ float rsh[2][256];
    int bp = blockIdx.x;            // batch pair: b = 2*bp, 2*bp+1
    int kg = blockIdx.y;            // k in kg*6 .. kg*6+5
    int tid = threadIdx.x;
    int l = tid >> 6, m = tid & 63;

    const float* g0 = x + (size_t)(2 * bp) * 3072;
    #pragma unroll
    for (int p = 0; p < 3; ++p) {
        ((float4*)xb0)[tid + p * 256] = ((const float4*)g0)[tid + p * 256];
        ((float4*)xb1)[tid + p * 256] = ((const float4*)(g0 + 3072))[tid + p * 256];
    }
    __syncthreads();

    for (int kk = 0; kk < 6; ++kk) {
        int k = kg * 6 + kk;
        int cbase = k * 4 + l;
        float r0 = 0.f, r1 = 0.f;
        #pragma unroll 8
        for (int ij = 0; ij < 48; ++ij) {
            float c = C1[ij * 48 + cbase];        // wave-uniform -> s_load
            r0 += c * xb0[ij * 64 + m];
            r1 += c * xb1[ij * 64 + m];
        }
        rsh[0][tid] = r0; rsh[1][tid] = r1;
        __syncthreads();

        const float* Wkl = W1 + (size_t)(k * 4 + l) * 4096;
        float acc0 = b1[(k * 4 + l) * 64 + m];
        float acc1 = acc0;
        const float* r0p = &rsh[0][l * 64];
        const float* r1p = &rsh[1][l * 64];
        #pragma unroll 8
        for (int mm = 0; mm < 64; ++mm) {
            float w = Wkl[mm * 64 + m];
            acc0 += r0p[mm] * w;
            acc1 += r1p[mm] * w;
        }
        size_t o = (size_t)(2 * bp) * 3072 + k * 256 + l * 64 + m;
        xp[o] = fmaxf(acc0, 0.f);
        xp[o + 3072] = fmaxf(acc1, 0.f);
        __syncthreads();
    }
}

// ---------------------------------------------------------------------------
// Capsule layer 2 + skip (fp32, exact). Grid (256, 2): 5 capsules per group.
// ---------------------------------------------------------------------------
__global__ __launch_bounds__(256) void caps2_kernel(
    const float* __restrict__ xp, const float* __restrict__ Cs,
    const float* __restrict__ C2, const float* __restrict__ W2,
    const float* __restrict__ b2, float* __restrict__ xsum)
{
    __shared__ float xb0[3072], xb1[3072];
    __shared__ float rsh[2][256];
    int bp = blockIdx.x;
    int kg = blockIdx.y;            // k in kg*5 .. kg*5+4
    int tid = threadIdx.x;
    int l = tid >> 6, m = tid & 63;

    const float* g0 = xp + (size_t)(2 * bp) * 3072;
    #pragma unroll
    for (int p = 0; p < 3; ++p) {
        ((float4*)xb0)[tid + p * 256] = ((const float4*)g0)[tid + p * 256];
        ((float4*)xb1)[tid + p * 256] = ((const float4*)(g0 + 3072))[tid + p * 256];
    }
    __syncthreads();

    for (int kk = 0; kk < 5; ++kk) {
        int k = kg * 5 + kk;
        int cbase = k * 4 + l;
        float r0 = 0.f, r1 = 0.f, sk0 = 0.f, sk1 = 0.f;
        #pragma unroll 8
        for (int ij = 0; ij < 48; ++ij) {
            float c2 = C2[ij * 40 + cbase];
            float cs = Cs[ij * 40 + cbase];
            float v0 = xb0[ij * 64 + m];
            float v1 = xb1[ij * 64 + m];
            r0 += c2 * v0;  r1 += c2 * v1;
            sk0 += cs * v0; sk1 += cs * v1;
        }
        rsh[0][tid] = r0; rsh[1][tid] = r1;
        __syncthreads();

        const float* Wkl = W2 + (size_t)(k * 4 + l) * 4096;
        float acc0 = b2[(k * 4 + l) * 64 + m];
        float acc1 = acc0;
        const float* r0p = &rsh[0][l * 64];
        const float* r1p = &rsh[1][l * 64];
        #pragma unroll 8
        for (int mm = 0; mm < 64; ++mm) {
            float w = Wkl[mm * 64 + m];
            acc0 += r0p[mm] * w;
            acc1 += r1p[mm] * w;
        }
        size_t o = (size_t)(2 * bp) * 2560 + k * 256 + l * 64 + m;
        xsum[o] = sk0 + fmaxf(acc0, 0.f);
        xsum[o + 2560] = sk1 + fmaxf(acc1, 0.f);
        __syncthreads();
    }
}

// ---------------------------------------------------------------------------
// Norm/argmax/mask; writes x_recon as bf16
// ---------------------------------------------------------------------------
__global__ __launch_bounds__(256) void mask_kernel(
    const float* __restrict__ xs, unsigned short* __restrict__ xrec)
{
    int b = blockIdx.x;
    int tid = threadIdx.x;
    int lane = tid & 63, wave = tid >> 6;
    __shared__ float part[4][10];
    __shared__ int act_sh;

    const float* xb = xs + b * 2560;
    for (int cap = 0; cap < 10; ++cap) {
        float v = xb[cap * 256 + tid];
        v = v * v;
        #pragma unroll
        for (int off = 32; off >= 1; off >>= 1)
            v += __shfl_down(v, off);
        if (lane == 0) part[wave][cap] = v;
    }
    __syncthreads();
    if (tid == 0) {
        int best = 0;
        float bn = -1.f;
        for (int cap = 0; cap < 10; ++cap) {
            float s = part[0][cap] + part[1][cap] + part[2][cap] + part[3][cap];
            if (s > bn) { bn = s; best = cap; }
        }
        act_sh = best;
    }
    __syncthreads();
    int act = act_sh;
    unsigned short* xr = xrec + b * 2560;
    #pragma unroll
    for (int r = 0; r < 10; ++r) {
        int idx = tid + r * 256;
        int cap = idx >> 8;
        float v = (cap == act) ? xb[idx] : 0.f;
        xr[idx] = f2bf(v);
    }
}

// ---------------------------------------------------------------------------
// Weight convert+transpose: W[Kr][Nr] f32 -> Wt[Np][Kp] bf16, zero-padded.
// 64x64 tile. Load: float4 global reads -> 4 scalar LDS writes, stride 65
// (odd stride -> 2-way banking, free). Store: 16 strided LDS reads (2-way),
// pack bf16, two 16B global stores per thread. Grid (Kp/64, Np/64).
// ---------------------------------------------------------------------------
__global__ __launch_bounds__(256) void convT_kernel(
    const float* __restrict__ W, unsigned short* __restrict__ Wt,
    int Kr, int Nr, int Kp, int Np)
{
    __shared__ float t[64 * 65];   // [k][n], stride 65 floats
    int k0 = blockIdx.x * 64;
    int n0 = blockIdx.y * 64;
    int tid = threadIdx.x;

    // load phase
    {
        int kr = tid >> 4;             // 0..15
        int nc = (tid & 15) * 4;       // 0..60
        #pragma unroll
        for (int p = 0; p < 4; ++p) {
            int k = k0 + kr + p * 16;
            float4 v = make_float4(0.f, 0.f, 0.f, 0.f);
            if (k < Kr) {
                if (n0 + nc + 3 < Nr) {
                    v = *(const float4*)&W[(size_t)k * Nr + n0 + nc];
                } else {
                    float tmp[4] = {0.f, 0.f, 0.f, 0.f};
                    #pragma unroll
                    for (int j = 0; j < 4; ++j)
                        if (n0 + nc + j < Nr) tmp[j] = W[(size_t)k * Nr + n0 + nc + j];
                    v = make_float4(tmp[0], tmp[1], tmp[2], tmp[3]);
                }
            }
            float* row = &t[(kr + p * 16) * 65 + nc];
            row[0] = v.x; row[1] = v.y; row[2] = v.z; row[3] = v.w;
        }
    }
    __syncthreads();

    // store phase: thread -> (row n, 16 consecutive k)
    {
        int nr = tid >> 2;             // 0..63
        int kc = (tid & 3) * 16;       // 0,16,32,48
        unsigned int u[8];
        #pragma unroll
        for (int j = 0; j < 8; ++j) {
            float v0 = t[(kc + 2 * j)     * 65 + nr];
            float v1 = t[(kc + 2 * j + 1) * 65 + nr];
            u[j] = (unsigned int)f2bf(v0) | ((unsigned int)f2bf(v1) << 16);
        }
        unsigned int* dst = (unsigned int*)&Wt[(size_t)(n0 + nr) * Kp + k0 + kc];
        *(uint4*)(dst)     = make_uint4(u[0], u[1], u[2], u[3]);
        *(uint4*)(dst + 4) = make_uint4(u[4], u[5], u[6], u[7]);
    }
}

// ---------------------------------------------------------------------------
// Split-K MFMA GEMM (m97 structure): P[z] = A[M,Kp] @ Bt[Np,Kp]^T slice
// 128x128 tile, BK=32, 4 waves (2x2), 4x4 frags of 16x16x32.
// ---------------------------------------------------------------------------
#define SPLITK 4
__global__ __launch_bounds__(256) void gemm_splitk(
    const unsigned short* __restrict__ A, int ldA,
    const unsigned short* __restrict__ Bt, int ldB,
    float* __restrict__ P, int Np, int kper)
{
    __shared__ __align__(16) unsigned short As[128 * 32];
    __shared__ __align__(16) unsigned short Bs[128 * 32];

    int tid = threadIdx.x;
    int bn = blockIdx.x * 128;
    int bm = blockIdx.y * 128;
    int kz = blockIdx.z * kper;

    int w = tid >> 6, lane = tid & 63;
    int wm = (w >> 1) * 64, wn = (w & 1) * 64;
    int q = lane >> 4, r16 = lane & 15;

    int srow = tid >> 2, skq = tid & 3;

    f32x4 acc[4][4];
    #pragma unroll
    for (int i = 0; i < 4; ++i)
        #pragma unroll
        for (int j = 0; j < 4; ++j) acc[i][j] = (f32x4)0.f;

    for (int kk = 0; kk < kper; kk += 32) {
        int k0 = kz + kk;
        const unsigned short* ga = A + (size_t)(bm + srow) * ldA + k0 + skq * 8;
        GLD16(ga, &As[tid * 8]);
        GLD16(ga + (size_t)64 * ldA, &As[(tid + 256) * 8]);
        const unsigned short* gb = Bt + (size_t)(bn + srow) * ldB + k0 + skq * 8;
        GLD16(gb, &Bs[tid * 8]);
        GLD16(gb + (size_t)64 * ldB, &Bs[(tid + 256) * 8]);
        __syncthreads();

        short8 a[4], b[4];
        #pragma unroll
        for (int mt = 0; mt < 4; ++mt)
            a[mt] = *(const short8*)&As[(wm + mt * 16 + r16) * 32 + q * 8];
        #pragma unroll
        for (int nt = 0; nt < 4; ++nt)
            b[nt] = *(const short8*)&Bs[(wn + nt * 16 + r16) * 32 + q * 8];
        #pragma unroll
        for (int mt = 0; mt < 4; ++mt)
            #pragma unroll
            for (int nt = 0; nt < 4; ++nt)
                acc[mt][nt] = __builtin_amdgcn_mfma_f32_16x16x32_bf16(a[mt], b[nt], acc[mt][nt], 0, 0, 0);
        __syncthreads();
    }

    float* Pz = P + (size_t)blockIdx.z * 512 * Np;
    #pragma unroll
    for (int mt = 0; mt < 4; ++mt) {
        #pragma unroll
        for (int nt = 0; nt < 4; ++nt) {
            int cn = bn + wn + nt * 16 + r16;
            #pragma unroll
            for (int reg = 0; reg < 4; ++reg) {
                int cm = bm + wm + mt * 16 + q * 4 + reg;
                Pz[(size_t)cm * Np + cn] = acc[mt][nt][reg];
            }
        }
    }
}

// ---------------------------------------------------------------------------
// Combine split-K partials + bias + act.
// MODE 0: relu -> bf16. MODE 1: sigmoid -> f32.
// ---------------------------------------------------------------------------
template<int MODE>
__global__ __launch_bounds__(256) void combine_kernel(
    const float* __restrict__ P, const float* __restrict__ bias,
    void* __restrict__ out, int Np, int N_real)
{
    int gid = blockIdx.x * 256 + threadIdx.x;
    int n0 = (gid * 4) % Np;
    int m  = (gid * 4) / Np;
    size_t MN = (size_t)512 * Np;
    const float* p = P + (size_t)m * Np + n0;
    f32x4 s = *(const f32x4*)p;
    s += *(const f32x4*)(p + MN);
    s += *(const f32x4*)(p + 2 * MN);
    s += *(const f32x4*)(p + 3 * MN);
    f32x4 bv = (n0 < N_real) ? *(const f32x4*)(bias + n0) : (f32x4)0.f;
    s += bv;
    if (MODE == 0) {
        unsigned int lo = (unsigned int)f2bf(fmaxf(s[0], 0.f)) | ((unsigned int)f2bf(fmaxf(s[1], 0.f)) << 16);
        unsigned int hi = (unsigned int)f2bf(fmaxf(s[2], 0.f)) | ((unsigned int)f2bf(fmaxf(s[3], 0.f)) << 16);
        *(uint2*)((unsigned short*)out + (size_t)m * Np + n0) = make_uint2(lo, hi);
    } else {
        f32x4 v;
        v[0] = 1.f / (1.f + expf(-s[0]));
        v[1] = 1.f / (1.f + expf(-s[1]));
        v[2] = 1.f / (1.f + expf(-s[2]));
        v[3] = 1.f / (1.f + expf(-s[3]));
        *(f32x4*)((float*)out + (size_t)m * Np + n0) = v;
    }
}

extern "C" void kernel_launch(void* const* d_in, const int* in_sizes, int n_in,
                              void* d_out, int out_size, void* d_ws, size_t ws_size,
                              hipStream_t stream) {
    const float* x   = (const float*)d_in[0];
    const float* C1  = (const float*)d_in[1];
    const float* W1  = (const float*)d_in[2];
    const float* b1  = (const float*)d_in[3];
    const float* Cs  = (const float*)d_in[4];
    const float* C2  = (const float*)d_in[5];
    const float* W2  = (const float*)d_in[6];
    const float* b2  = (const float*)d_in[7];
    const float* Wr1 = (const float*)d_in[8];
    const float* br1 = (const float*)d_in[9];
    const float* Wr2 = (const float*)d_in[10];
    const float* br2 = (const float*)d_in[11];
    const float* Wr3 = (const float*)d_in[12];
    const float* br3 = (const float*)d_in[13];

    float* out = (float*)d_out;
    float* out0     = out;              // (512,3072) f32 sigmoid output
    float* xsum_out = out + OUT0_SZ;    // (512,2560) f32 x_sum (exact)

    // workspace layout (bytes)
    char* base = (char*)d_ws;
    float*          xp   = (float*)(base);                      //  6,291,456
    unsigned short* xrec = (unsigned short*)(base +  6291456);  //  2,621,440
    unsigned short* h1   = (unsigned short*)(base +  8912896);  //  5,242,880
    unsigned short* h2   = (unsigned short*)(base + 14155776);  //  4,194,304
    unsigned short* Wt   = (unsigned short*)(base + 18350080);  // 41,943,040
    float*          Pbuf = (float*)(base + 60293120);           // 41,943,040
    // total: 102,236,160 B

    // --- capsule path (exact fp32 -> output 1) ---
    caps1_kernel<<<dim3(256, 2), 256, 0, stream>>>(x, C1, W1, b1, xp);
    caps2_kernel<<<dim3(256, 2), 256, 0, stream>>>(xp, Cs, C2, W2, b2, xsum_out);
    mask_kernel<<<BATCH, 256, 0, stream>>>(xsum_out, xrec);

    // --- layer 1: (512,2560) @ (2560,5000) -> h1 (512,5120 bf16) ---
    convT_kernel<<<dim3(2560 / 64, 5120 / 64), 256, 0, stream>>>(Wr1, Wt, 2560, 5000, 2560, 5120);
    gemm_splitk<<<dim3(5120 / 128, 4, SPLITK), 256, 0, stream>>>(xrec, 2560, Wt, 2560, Pbuf, 5120, 2560 / SPLITK);
    combine_kernel<0><<<512 * 5120 / 1024, 256, 0, stream>>>(Pbuf, br1, h1, 5120, 5000);

    // --- layer 2: (512,5120) @ (5120,4000) -> h2 (512,4096 bf16) ---
    convT_kernel<<<dim3(5120 / 64, 4096 / 64), 256, 0, stream>>>(Wr2, Wt, 5000, 4000, 5120, 4096);
    gemm_splitk<<<dim3(4096 / 128, 4, SPLITK), 256, 0, stream>>>(h1, 5120, Wt, 5120, Pbuf, 4096, 5120 / SPLITK);
    combine_kernel<0><<<512 * 4096 / 1024, 256, 0, stream>>>(Pbuf, br2, h2, 4096, 4000);

    // --- layer 3: (512,4096) @ (4096,3072) -> out0 (512,3072 f32, sigmoid) ---
    convT_kernel<<<dim3(4096 / 64, 3072 / 64), 256, 0, stream>>>(Wr3, Wt, 4000, 3072, 4096, 3072);
    gemm_splitk<<<dim3(3072 / 128, 4, SPLITK), 256, 0, stream>>>(h2, 4096, Wt, 4096, Pbuf, 3072, 4096 / SPLITK);
    combine_kernel<1><<<512 * 3072 / 1024, 256, 0, stream>>>(Pbuf, br3, out0, 3072, 3072);
}